// Round 1
// baseline (346.403 us; speedup 1.0000x reference)
//
#include <hip/hip_runtime.h>
#include <hip/hip_bf16.h>

// ---------------------------------------------------------------------------
// TinyMNISTNet: out = relu(x @ Wq1^T + b1) @ Wq2^T + b2, ternarized weights.
// x: [65536, 784] fp32; W1: [64,784]; b1:[64]; W2:[10,64]; b2:[10]; out fp32 [65536,10].
// Strategy: ternarize once (tiny), then one fused HBM-bound MFMA kernel.
// ---------------------------------------------------------------------------

typedef __attribute__((ext_vector_type(4))) float f32x4;
typedef __attribute__((ext_vector_type(8))) short s16x8;

#define K1 784
#define K1_PAD 800          // padded K for 25 full 32-wide MFMA steps
#define NHID 64
#define NOUT 10

// round-to-nearest-even f32 -> bf16 bits (inputs are finite, no NaN handling)
static __device__ __forceinline__ unsigned short f2bf_rne(float f) {
    unsigned int u = __builtin_bit_cast(unsigned int, f);
    unsigned int r = u + 0x7FFFu + ((u >> 16) & 1u);
    return (unsigned short)(r >> 16);
}

// ---------------------------------------------------------------------------
// Ternarize kernel: single block, 1024 threads. Double accumulation to track
// the numpy (fp64) reference's delta/alpha as closely as possible.
// ---------------------------------------------------------------------------
static __device__ double block_sum(double v, double* red) {
    #pragma unroll
    for (int off = 32; off > 0; off >>= 1) v += __shfl_down(v, off, 64);
    const int w = threadIdx.x >> 6;
    const int lane = threadIdx.x & 63;
    __syncthreads();                 // protect red[] reuse across calls
    if (lane == 0) red[w] = v;
    __syncthreads();
    if (threadIdx.x == 0) {
        double t = 0.0;
        #pragma unroll
        for (int i = 0; i < 16; ++i) t += red[i];
        red[0] = t;
    }
    __syncthreads();
    return red[0];
}

__global__ __launch_bounds__(1024) void ternarize_kernel(
    const float* __restrict__ W1, const float* __restrict__ W2,
    unsigned short* __restrict__ W1q, unsigned short* __restrict__ W2q,
    float* __restrict__ alphas)
{
    __shared__ double red[16];
    const int tid = threadIdx.x;

    // ---- W1: delta ----
    double s = 0.0;
    for (int i = tid; i < NHID * K1; i += 1024) s += (double)fabsf(W1[i]);
    s = block_sum(s, red);
    const float delta1 = (float)(0.7 * (s / (double)(NHID * K1)));

    // ---- W1: alpha ----
    double sm = 0.0, cn = 0.0;
    for (int i = tid; i < NHID * K1; i += 1024) {
        float a = fabsf(W1[i]);
        if (a > delta1) { sm += (double)a; cn += 1.0; }
    }
    sm = block_sum(sm, red);
    cn = block_sum(cn, red);
    const float alpha1 = (float)(sm / fmax(cn, 1.0));
    if (tid == 0) alphas[0] = alpha1;

    // ---- W1q: ternary signs as bf16, padded [64][800] ----
    for (int i = tid; i < NHID * K1_PAD; i += 1024) {
        int n = i / K1_PAD;
        int k = i - n * K1_PAD;
        unsigned short v = 0;
        if (k < K1) {
            float w = W1[n * K1 + k];
            if (fabsf(w) > delta1) v = (w > 0.0f) ? 0x3F80u : 0xBF80u;
        }
        W1q[i] = v;
    }

    // ---- W2: delta ----
    double s2 = 0.0;
    for (int i = tid; i < NOUT * NHID; i += 1024) s2 += (double)fabsf(W2[i]);
    s2 = block_sum(s2, red);
    const float delta2 = (float)(0.7 * (s2 / (double)(NOUT * NHID)));

    // ---- W2: alpha ----
    double sm2 = 0.0, cn2 = 0.0;
    for (int i = tid; i < NOUT * NHID; i += 1024) {
        float a = fabsf(W2[i]);
        if (a > delta2) { sm2 += (double)a; cn2 += 1.0; }
    }
    sm2 = block_sum(sm2, red);
    cn2 = block_sum(cn2, red);
    const float alpha2 = (float)(sm2 / fmax(cn2, 1.0));
    if (tid == 0) alphas[1] = alpha2;

    // ---- W2q: ternary signs as bf16, padded [16][64] (rows 10..15 zero) ----
    for (int i = tid; i < 16 * NHID; i += 1024) {
        int n = i >> 6;
        int k = i & 63;
        unsigned short v = 0;
        if (n < NOUT) {
            float w = W2[n * NHID + k];
            if (fabsf(w) > delta2) v = (w > 0.0f) ? 0x3F80u : 0xBF80u;
        }
        W2q[i] = v;
    }
}

// ---------------------------------------------------------------------------
// Fused 2-layer kernel. 256 threads = 4 waves; each wave computes 16 rows of
// the batch x all 64 hidden features (layer 1), then 16x10 outputs (layer 2).
// Grid: nrows/64 blocks.
//
// MFMA 16x16x32 bf16 layouts (m89/m91/m120-verified):
//   A[m = lane&15][k = (lane>>4)*8 + j]  (8 contiguous k per lane)
//   B[n = lane&15][k = (lane>>4)*8 + j]  (rows of the [N][K] matrix)
//   C/D: col = lane&15, row = (lane>>4)*4 + reg
// ---------------------------------------------------------------------------
__global__ __launch_bounds__(256) void fused_kernel(
    const float* __restrict__ x,
    const float* __restrict__ b1,
    const float* __restrict__ b2,
    const short* __restrict__ W1q,   // [64][800] bf16 signs
    const short* __restrict__ W2q,   // [16][64]  bf16 signs
    const float* __restrict__ alphas,
    float* __restrict__ out)
{
    const int tid  = threadIdx.x;
    const int wave = tid >> 6;
    const int lane = tid & 63;
    const int low  = lane & 15;
    const int quad = lane >> 4;

    const int m0 = blockIdx.x * 64 + wave * 16;   // this wave's row base
    const float* xrow = x + (size_t)(m0 + low) * K1;

    f32x4 acc[4];
    #pragma unroll
    for (int nt = 0; nt < 4; ++nt) acc[nt] = (f32x4){0.f, 0.f, 0.f, 0.f};

    // ---- layer 1: 25 K-steps of 32 ----
    for (int ks = 0; ks < 25; ++ks) {
        const int kf = ks * 32 + quad * 8;   // this lane's 8-wide k slice
        s16x8 a;
        if (kf + 8 <= K1) {
            f32x4 p = *(const f32x4*)(xrow + kf);
            f32x4 q = *(const f32x4*)(xrow + kf + 4);
            a[0] = (short)f2bf_rne(p[0]); a[1] = (short)f2bf_rne(p[1]);
            a[2] = (short)f2bf_rne(p[2]); a[3] = (short)f2bf_rne(p[3]);
            a[4] = (short)f2bf_rne(q[0]); a[5] = (short)f2bf_rne(q[1]);
            a[6] = (short)f2bf_rne(q[2]); a[7] = (short)f2bf_rne(q[3]);
        } else {
            a = (s16x8)(short)0;          // tail pad (k >= 784)
        }
        s16x8 b[4];
        #pragma unroll
        for (int nt = 0; nt < 4; ++nt)
            b[nt] = *(const s16x8*)(W1q + (size_t)(nt * 16 + low) * K1_PAD + kf);
        #pragma unroll
        for (int nt = 0; nt < 4; ++nt)
            acc[nt] = __builtin_amdgcn_mfma_f32_16x16x32_bf16(a, b[nt], acc[nt], 0, 0, 0);
    }

    // ---- epilogue 1: alpha1*acc + b1, relu, bf16 -> LDS (C-layout -> A-layout) ----
    const float alpha1 = alphas[0];
    const float alpha2 = alphas[1];

    __shared__ __align__(16) unsigned short h_lds[4][16][72];  // stride 72 breaks bank stride
    #pragma unroll
    for (int nt = 0; nt < 4; ++nt) {
        const int n = nt * 16 + low;
        const float bias = b1[n];
        #pragma unroll
        for (int r = 0; r < 4; ++r) {
            float hv = fmaxf(0.0f, fmaf(alpha1, acc[nt][r], bias));
            h_lds[wave][quad * 4 + r][n] = f2bf_rne(hv);
        }
    }
    __syncthreads();

    // ---- layer 2: [16x64] x [64x16] via 2 MFMA steps ----
    s16x8 a0 = *(const s16x8*)(&h_lds[wave][low][quad * 8]);
    s16x8 a1 = *(const s16x8*)(&h_lds[wave][low][32 + quad * 8]);
    s16x8 w0 = *(const s16x8*)(W2q + low * 64 + quad * 8);
    s16x8 w1 = *(const s16x8*)(W2q + low * 64 + 32 + quad * 8);

    f32x4 acc2 = (f32x4){0.f, 0.f, 0.f, 0.f};
    acc2 = __builtin_amdgcn_mfma_f32_16x16x32_bf16(a0, w0, acc2, 0, 0, 0);
    acc2 = __builtin_amdgcn_mfma_f32_16x16x32_bf16(a1, w1, acc2, 0, 0, 0);

    // ---- epilogue 2: alpha2*acc2 + b2, store fp32 ----
    if (low < NOUT) {
        const float bias2 = b2[low];
        #pragma unroll
        for (int r = 0; r < 4; ++r) {
            const int row = m0 + quad * 4 + r;
            out[(size_t)row * NOUT + low] = fmaf(alpha2, acc2[r], bias2);
        }
    }
}

// ---------------------------------------------------------------------------
extern "C" void kernel_launch(void* const* d_in, const int* in_sizes, int n_in,
                              void* d_out, int out_size, void* d_ws, size_t ws_size,
                              hipStream_t stream) {
    const float* x  = (const float*)d_in[0];
    const float* W1 = (const float*)d_in[1];
    const float* b1 = (const float*)d_in[2];
    const float* W2 = (const float*)d_in[3];
    const float* b2 = (const float*)d_in[4];
    float* out = (float*)d_out;

    const int nrows = in_sizes[0] / K1;   // 65536

    // ws layout: W1q [64*800] bf16 | W2q [16*64] bf16 | alphas [2] f32
    unsigned short* W1q = (unsigned short*)d_ws;
    unsigned short* W2q = W1q + NHID * K1_PAD;
    float* alphas = (float*)(W2q + 16 * NHID);

    ternarize_kernel<<<1, 1024, 0, stream>>>(W1, W2, W1q, W2q, alphas);

    const int nblocks = nrows / 64;       // 64 rows per block (16 per wave)
    fused_kernel<<<nblocks, 256, 0, stream>>>(x, b1, b2, (const short*)W1q,
                                              (const short*)W2q, alphas, out);
}

// Round 2
// 306.452 us; speedup vs baseline: 1.1304x; 1.1304x over previous
//
#include <hip/hip_runtime.h>
#include <hip/hip_bf16.h>

// ---------------------------------------------------------------------------
// TinyMNISTNet: out = relu(x @ Wq1^T + b1) @ Wq2^T + b2, ternarized weights.
// x: [65536,784] fp32; W1: [64,784]; b1:[64]; W2:[10,64]; b2:[10]; out fp32 [65536,10].
//
// R2: (a) parallel 2-kernel ternarize (64 blocks, f64 atomics) instead of the
//     single-block version; (b) fused kernel now stages x through wave-private
//     LDS with fully-coalesced 128B-per-row global loads and 1-chunk-deep
//     software prefetch, instead of 16-way-split direct loads.
// ---------------------------------------------------------------------------

typedef __attribute__((ext_vector_type(4))) float f32x4;
typedef __attribute__((ext_vector_type(8))) short s16x8;
typedef __attribute__((ext_vector_type(4))) short s16x4;

#define K1 784
#define K1_PAD 800          // 25 K-steps of 32
#define NHID 64
#define NOUT 10

// round-to-nearest-even f32 -> bf16 bits (finite inputs)
static __device__ __forceinline__ unsigned short f2bf_rne(float f) {
    unsigned int u = __builtin_bit_cast(unsigned int, f);
    unsigned int r = u + 0x7FFFu + ((u >> 16) & 1u);
    return (unsigned short)(r >> 16);
}

// block-wide f64 sum for 256-thread blocks (4 waves)
static __device__ double block_sum256(double v, double* red) {
    #pragma unroll
    for (int off = 32; off > 0; off >>= 1) v += __shfl_down(v, off, 64);
    const int w = threadIdx.x >> 6;
    const int lane = threadIdx.x & 63;
    __syncthreads();                 // protect red[] reuse across calls
    if (lane == 0) red[w] = v;
    __syncthreads();
    return red[0] + red[1] + red[2] + red[3];
}

// ---------------------------------------------------------------------------
// hdr layout (doubles): [0]=sumabs(W1) [1]=sumabs(W2) [2]=sm1 [3]=cn1 [4]=sm2 [5]=cn2
// ---------------------------------------------------------------------------
__global__ __launch_bounds__(256) void tern_sum_kernel(
    const float* __restrict__ W1, const float* __restrict__ W2,
    double* __restrict__ hdr)
{
    __shared__ double red[4];
    double s = 0.0;
    for (int i = blockIdx.x * 256 + threadIdx.x; i < NHID * K1; i += gridDim.x * 256)
        s += (double)fabsf(W1[i]);
    s = block_sum256(s, red);
    if (threadIdx.x == 0) atomicAdd(&hdr[0], s);

    if (blockIdx.x == 0) {
        double s2 = 0.0;
        for (int i = threadIdx.x; i < NOUT * NHID; i += 256)
            s2 += (double)fabsf(W2[i]);
        s2 = block_sum256(s2, red);
        if (threadIdx.x == 0) atomicAdd(&hdr[1], s2);
    }
}

__global__ __launch_bounds__(256) void tern_quant_kernel(
    const float* __restrict__ W1, const float* __restrict__ W2,
    unsigned short* __restrict__ W1q, unsigned short* __restrict__ W2q,
    double* __restrict__ hdr)
{
    __shared__ double red[4];
    const float delta1 = (float)(0.7 * hdr[0] / (double)(NHID * K1));

    double sm = 0.0, cn = 0.0;
    for (int i = blockIdx.x * 256 + threadIdx.x; i < NHID * K1_PAD; i += gridDim.x * 256) {
        int n = i / K1_PAD;
        int k = i - n * K1_PAD;
        unsigned short v = 0;
        if (k < K1) {
            float w = W1[n * K1 + k];
            float a = fabsf(w);
            if (a > delta1) { v = (w > 0.0f) ? 0x3F80u : 0xBF80u; sm += (double)a; cn += 1.0; }
        }
        W1q[i] = v;
    }
    sm = block_sum256(sm, red);
    cn = block_sum256(cn, red);
    if (threadIdx.x == 0) { atomicAdd(&hdr[2], sm); atomicAdd(&hdr[3], cn); }

    if (blockIdx.x == 0) {
        const float delta2 = (float)(0.7 * hdr[1] / (double)(NOUT * NHID));
        double sm2 = 0.0, cn2 = 0.0;
        for (int i = threadIdx.x; i < 16 * NHID; i += 256) {
            int n = i >> 6;
            int k = i & 63;
            unsigned short v = 0;
            if (n < NOUT) {
                float w = W2[n * NHID + k];
                float a = fabsf(w);
                if (a > delta2) { v = (w > 0.0f) ? 0x3F80u : 0xBF80u; sm2 += (double)a; cn2 += 1.0; }
            }
            W2q[i] = v;
        }
        sm2 = block_sum256(sm2, red);
        cn2 = block_sum256(cn2, red);
        if (threadIdx.x == 0) { atomicAdd(&hdr[4], sm2); atomicAdd(&hdr[5], cn2); }
    }
}

// ---------------------------------------------------------------------------
// Fused 2-layer kernel. 256 threads = 4 waves; each wave: 16 batch rows x all
// 64 hidden features, then 16x10 outputs. Grid: nrows/64.
//
// Per K-step (32 floats/row), each wave stages its 16x32 fp32 tile:
//   sweep0: lane i loads rows m0+(i>>3), 16B at float (i&7)*4   -> 8x128B txns
//   sweep1: same for rows m0+8+(i>>3)
// convert to bf16, write to wave-private LDS (contiguous, conflict-free),
// read back MFMA A-fragments (lane: row=lane&15, k=quad*8). Double-buffered;
// next chunk's global loads issue one full iteration ahead.
//
// MFMA 16x16x32 bf16 layouts (m89/m91/m120-verified):
//   A[m=lane&15][k=quad*8+j], B[n=lane&15][k=quad*8+j], C/D: col=lane&15, row=quad*4+reg
// ---------------------------------------------------------------------------
__global__ __launch_bounds__(256) void fused_kernel(
    const float* __restrict__ x,
    const float* __restrict__ b1,
    const float* __restrict__ b2,
    const short* __restrict__ W1q,   // [64][800] bf16 signs
    const short* __restrict__ W2q,   // [16][64]  bf16 signs
    const double* __restrict__ hdr,
    float* __restrict__ out)
{
    const int tid  = threadIdx.x;
    const int wave = tid >> 6;
    const int lane = tid & 63;
    const int low  = lane & 15;
    const int quad = lane >> 4;

    const int m0 = blockIdx.x * 64 + wave * 16;

    // staging-load role: 8 lanes per row, 16B per lane (contiguous 128B/row)
    const int srow = lane >> 3;      // 0..7
    const int scol = lane & 7;       // *4 floats = *16 bytes
    const float* g0 = x + (size_t)(m0 + srow) * K1 + scol * 4;
    const float* g1 = x + (size_t)(m0 + 8 + srow) * K1 + scol * 4;

    // wave-private double-buffered A-stage: [wave][buf][row 16][k 32] bf16 = 1KB/buf
    __shared__ __align__(16) unsigned short stage[4][2][16][32];
    __shared__ __align__(16) unsigned short h_lds[4][16][72];  // layer-2 A staging

    const short* wbase = W1q + (size_t)low * K1_PAD + quad * 8;

    f32x4 acc[4];
    #pragma unroll
    for (int nt = 0; nt < 4; ++nt) acc[nt] = (f32x4){0.f, 0.f, 0.f, 0.f};

    const f32x4 zero4 = (f32x4){0.f, 0.f, 0.f, 0.f};

    // prologue: load chunk 0
    f32x4 c0 = *(const f32x4*)(g0);
    f32x4 c1 = *(const f32x4*)(g1);

    int buf = 0;
    for (int ks = 0; ks < 25; ++ks) {
        // prefetch next chunk (full iteration of latency hiding)
        f32x4 n0 = zero4, n1 = zero4;
        if (ks < 24) {
            const int kf = (ks + 1) * 32 + scol * 4;
            if (kf < K1) {               // tail chunk 24: only scol<4 valid
                n0 = *(const f32x4*)(g0 + (ks + 1) * 32);
                n1 = *(const f32x4*)(g1 + (ks + 1) * 32);
            }
        }

        // convert current chunk -> bf16, stash to LDS (lane-contiguous b64s)
        s16x4 p0, p1;
        p0[0] = (short)f2bf_rne(c0[0]); p0[1] = (short)f2bf_rne(c0[1]);
        p0[2] = (short)f2bf_rne(c0[2]); p0[3] = (short)f2bf_rne(c0[3]);
        p1[0] = (short)f2bf_rne(c1[0]); p1[1] = (short)f2bf_rne(c1[1]);
        p1[2] = (short)f2bf_rne(c1[2]); p1[3] = (short)f2bf_rne(c1[3]);
        *(s16x4*)&stage[wave][buf][srow][scol * 4]     = p0;
        *(s16x4*)&stage[wave][buf][8 + srow][scol * 4] = p1;

        // wave-private LDS write->cross-lane read: drain DS pipe explicitly
        __asm__ volatile("s_waitcnt lgkmcnt(0)" ::: "memory");

        s16x8 a = *(const s16x8*)&stage[wave][buf][low][quad * 8];
        const short* wk = wbase + ks * 32;
        #pragma unroll
        for (int nt = 0; nt < 4; ++nt) {
            s16x8 b = *(const s16x8*)(wk + (size_t)nt * 16 * K1_PAD);
            acc[nt] = __builtin_amdgcn_mfma_f32_16x16x32_bf16(a, b, acc[nt], 0, 0, 0);
        }

        c0 = n0; c1 = n1; buf ^= 1;
    }

    // ---- epilogue 1: alpha1*acc + b1, relu, bf16 -> LDS (C-layout -> A-layout) ----
    const float alpha1 = (float)(hdr[2] / fmax(hdr[3], 1.0));
    const float alpha2 = (float)(hdr[4] / fmax(hdr[5], 1.0));

    #pragma unroll
    for (int nt = 0; nt < 4; ++nt) {
        const int n = nt * 16 + low;
        const float bias = b1[n];
        #pragma unroll
        for (int r = 0; r < 4; ++r) {
            float hv = fmaxf(0.0f, fmaf(alpha1, acc[nt][r], bias));
            h_lds[wave][quad * 4 + r][n] = f2bf_rne(hv);
        }
    }
    __asm__ volatile("s_waitcnt lgkmcnt(0)" ::: "memory");

    // ---- layer 2: [16x64] x [64x16] via 2 MFMA steps ----
    s16x8 a0 = *(const s16x8*)(&h_lds[wave][low][quad * 8]);
    s16x8 a1 = *(const s16x8*)(&h_lds[wave][low][32 + quad * 8]);
    s16x8 w0 = *(const s16x8*)(W2q + low * 64 + quad * 8);
    s16x8 w1 = *(const s16x8*)(W2q + low * 64 + 32 + quad * 8);

    f32x4 acc2 = (f32x4){0.f, 0.f, 0.f, 0.f};
    acc2 = __builtin_amdgcn_mfma_f32_16x16x32_bf16(a0, w0, acc2, 0, 0, 0);
    acc2 = __builtin_amdgcn_mfma_f32_16x16x32_bf16(a1, w1, acc2, 0, 0, 0);

    // ---- epilogue 2: alpha2*acc2 + b2, store fp32 ----
    if (low < NOUT) {
        const float bias2 = b2[low];
        #pragma unroll
        for (int r = 0; r < 4; ++r) {
            const int row = m0 + quad * 4 + r;
            out[(size_t)row * NOUT + low] = fmaf(alpha2, acc2[r], bias2);
        }
    }
}

// ---------------------------------------------------------------------------
extern "C" void kernel_launch(void* const* d_in, const int* in_sizes, int n_in,
                              void* d_out, int out_size, void* d_ws, size_t ws_size,
                              hipStream_t stream) {
    const float* x  = (const float*)d_in[0];
    const float* W1 = (const float*)d_in[1];
    const float* b1 = (const float*)d_in[2];
    const float* W2 = (const float*)d_in[3];
    const float* b2 = (const float*)d_in[4];
    float* out = (float*)d_out;

    const int nrows = in_sizes[0] / K1;   // 65536

    // ws layout: hdr 6 doubles (64B aligned block) | W1q [64*800] bf16 | W2q [16*64] bf16
    double* hdr = (double*)d_ws;
    unsigned short* W1q = (unsigned short*)((char*)d_ws + 64);
    unsigned short* W2q = W1q + NHID * K1_PAD;

    hipMemsetAsync(d_ws, 0, 64, stream);  // zero atomic accumulators

    tern_sum_kernel<<<64, 256, 0, stream>>>(W1, W2, hdr);
    tern_quant_kernel<<<64, 256, 0, stream>>>(W1, W2, W1q, W2q, hdr);

    const int nblocks = nrows / 64;       // 64 rows per block (16 per wave)
    fused_kernel<<<nblocks, 256, 0, stream>>>(x, b1, b2, (const short*)W1q,
                                              (const short*)W2q, hdr, out);
}